// Round 9
// baseline (10470.145 us; speedup 1.0000x reference)
//
#include <hip/hip_runtime.h>

// Problem constants
#define BB 2048   // batch
#define TT 128    // timesteps
#define VV 25     // input features
#define HH 512    // hidden
#define NC 100    // classes

typedef __attribute__((ext_vector_type(8))) short short8;
typedef __attribute__((ext_vector_type(4))) float f32x4;

__device__ __forceinline__ float fsigmoid(float x) { return 1.0f / (1.0f + __expf(-x)); }
__device__ __forceinline__ float ftanh(float x) {
    float e = __expf(2.0f * x);
    return 1.0f - 2.0f / (e + 1.0f);
}

// fp32 -> bf16 hi + bf16 lo (RNE both); hi+lo carries ~16 mantissa bits.
__device__ __forceinline__ void split2(float f, short& hi, short& lo) {
    unsigned u = __float_as_uint(f);
    unsigned hb = (u + 0x7FFFu + ((u >> 16) & 1u)) >> 16;
    float hf = __uint_as_float(hb << 16);
    float r = f - hf;                      // exact
    unsigned v = __float_as_uint(r);
    unsigned lb = (v + 0x7FFFu + ((v >> 16) & 1u)) >> 16;
    hi = (short)hb;
    lo = (short)lb;
}
__device__ __forceinline__ short bf16rne(float f) {
    unsigned u = __float_as_uint(f);
    return (short)((u + 0x7FFFu + ((u >> 16) & 1u)) >> 16);
}

// ---- prep: weights -> MFMA-fragment-native bf16 layout ----
// WT[kq][n] : 16B group = bf16(W[n][kq*8 .. kq*8+7])  (kq 0..63 = W_hh,
// 64..67 = W_ih zero-padded to K=32).
__global__ __launch_bounds__(256) void prep_whh_t(const float* __restrict__ W,
                                                  short* __restrict__ WTh) {
    int i = blockIdx.x * 256 + threadIdx.x;   // 2048 n x 64 kq, grid 512
    int n = i & 2047, kq = i >> 11;
    short8 h8;
    #pragma unroll
    for (int j = 0; j < 8; ++j) h8[j] = bf16rne(W[(size_t)n * HH + kq * 8 + j]);
    ((short8*)WTh)[(size_t)kq * 2048 + n] = h8;
}

__global__ __launch_bounds__(256) void prep_wih_t(const float* __restrict__ W,
                                                  short* __restrict__ WTh) {
    int i = blockIdx.x * 256 + threadIdx.x;   // 2048 n x 4 kq, grid 32
    int n = i & 2047, kq4 = i >> 11;
    short8 h8;
    #pragma unroll
    for (int j = 0; j < 8; ++j) {
        int k = kq4 * 8 + j;
        h8[j] = (k < VV) ? bf16rne(W[(size_t)n * VV + k]) : (short)0;
    }
    ((short8*)WTh)[(size_t)(64 + kq4) * 2048 + n] = h8;
}

// PERSISTENT LSTM: one launch runs all 128 timesteps. Grid = 256 blocks
// (1/CU, all co-resident by construction: 256 thr, ~380 VGPR at
// __launch_bounds__(256,1) -> 1 block/CU, grid == CU count).
// Block (bp = bid>>4, by = bid&15) owns batch rows [bp*128, bp*128+128) and
// j-group [by*32, by*32+32) for all 4 gates. Its W fragments (4 gates x 17
// K-chunks x 16B/lane = 272 VGPR) are loaded ONCE and stay in registers for
// all steps — the r8 B-stream (139 MB/step of L2 traffic) goes to zero.
// Cross-step dependency: only the 16 by-blocks sharing bp exchange h slices
// -> per-bp generation-counter barrier (device-scope atomics + threadfence,
// G16). A (h hi/lo) staged via double-buffered LDS as in r8.
// 2-product split: acc += Ah*Bh + Al*Bh.
__global__ __launch_bounds__(256, 1) void lstm_persist(
    const float* __restrict__ msg,
    const short* __restrict__ WTh,
    const float* __restrict__ b_ih, const float* __restrict__ b_hh,
    short* __restrict__ h0h, short* __restrict__ h0l,
    short* __restrict__ h1h, short* __restrict__ h1l,
    float* __restrict__ c, int* __restrict__ syncc)
{
    const int bp = blockIdx.x >> 4;
    const int by = blockIdx.x & 15;
    const int j0 = by * 32;
    const int tid = threadIdx.x;
    const int lane = tid & 63;
    const int w = tid >> 6;
    const int wm = w & 1, wn = w >> 1;
    const int col = lane & 15, quad = lane >> 4;
    const int jj = j0 + wn * 16 + col;

    // [buf][plane][row][k]; row stride 72 (pad 8): frag b128 reads conflict-free
    __shared__ short Abuf[2][2][64][72];   // 36.9 KB

    // ---- W fragments resident in VGPRs for the whole kernel ----
    const short8* WTh8 = (const short8*)WTh;
    short8 Breg[17][4];
    {
        const int base = quad * 2048 + j0 + wn * 16 + col;
        #pragma unroll
        for (int cc = 0; cc < 17; ++cc)
            #pragma unroll
            for (int g = 0; g < 4; ++g)
                Breg[cc][g] = WTh8[(size_t)cc * 8192 + g * HH + base];
    }
    float bias[4];
    #pragma unroll
    for (int g = 0; g < 4; ++g) bias[g] = b_ih[g * HH + jj] + b_hh[g * HH + jj];

    const int arow = tid >> 2, aseg = (tid & 3) << 4;
    const int xseg = (tid & 3) << 3;

    for (int t = 0; t < TT; ++t) {
        const short* hinh = (t & 1) ? h1h : h0h;
        const short* hinl = (t & 1) ? h1l : h0l;
        short* houth = (t & 1) ? h0h : h1h;
        short* houtl = (t & 1) ? h0l : h1l;

        for (int tile = 0; tile < 2; ++tile) {
            const int b0 = bp * 128 + tile * 64;
            const short* aph = hinh + (size_t)(b0 + arow) * HH + aseg;
            const short* apl = hinl + (size_t)(b0 + arow) * HH + aseg;

            f32x4 acc[2][4];   // [tm][gate]
            #pragma unroll
            for (int g = 0; g < 4; ++g) {
                f32x4 bv = {bias[g], bias[g], bias[g], bias[g]};
                acc[0][g] = bv;
                acc[1][g] = bv;
            }

            short8 ra_h[2], ra_l[2];
            // prologue: chunk0 -> LDS buf0, chunk1 -> ra
            ra_h[0] = *(const short8*)(aph);      ra_h[1] = *(const short8*)(aph + 8);
            ra_l[0] = *(const short8*)(apl);      ra_l[1] = *(const short8*)(apl + 8);
            __syncthreads();   // prev tile/step frag reads done before overwrite
            *(short8*)&Abuf[0][0][arow][aseg]     = ra_h[0];
            *(short8*)&Abuf[0][0][arow][aseg + 8] = ra_h[1];
            *(short8*)&Abuf[0][1][arow][aseg]     = ra_l[0];
            *(short8*)&Abuf[0][1][arow][aseg + 8] = ra_l[1];
            ra_h[0] = *(const short8*)(aph + 64); ra_h[1] = *(const short8*)(aph + 72);
            ra_l[0] = *(const short8*)(apl + 64); ra_l[1] = *(const short8*)(apl + 72);
            __syncthreads();

            float xv[8];
            #pragma unroll
            for (int it = 0; it < 8; ++it) {
                const int buf = it & 1;
                #pragma unroll
                for (int kk = 0; kk < 2; ++kk) {
                    const int cchunk = it * 2 + kk;   // compile-time: Breg index
                    short8 ahf[2], alf[2];
                    #pragma unroll
                    for (int tm = 0; tm < 2; ++tm) {
                        int row = wm * 32 + tm * 16 + col;
                        ahf[tm] = *(const short8*)&Abuf[buf][0][row][kk * 32 + quad * 8];
                        alf[tm] = *(const short8*)&Abuf[buf][1][row][kk * 32 + quad * 8];
                    }
                    #pragma unroll
                    for (int tm = 0; tm < 2; ++tm)
                        #pragma unroll
                        for (int g = 0; g < 4; ++g) {
                            acc[tm][g] = __builtin_amdgcn_mfma_f32_16x16x32_bf16(ahf[tm], Breg[cchunk][g], acc[tm][g], 0, 0, 0);
                            acc[tm][g] = __builtin_amdgcn_mfma_f32_16x16x32_bf16(alf[tm], Breg[cchunk][g], acc[tm][g], 0, 0, 0);
                        }
                }
                if (it < 7) {
                    *(short8*)&Abuf[buf ^ 1][0][arow][aseg]     = ra_h[0];
                    *(short8*)&Abuf[buf ^ 1][0][arow][aseg + 8] = ra_h[1];
                    *(short8*)&Abuf[buf ^ 1][1][arow][aseg]     = ra_l[0];
                    *(short8*)&Abuf[buf ^ 1][1][arow][aseg + 8] = ra_l[1];
                    if (it < 6) {
                        const int kt = (it + 2) * 64;
                        ra_h[0] = *(const short8*)(aph + kt); ra_h[1] = *(const short8*)(aph + kt + 8);
                        ra_l[0] = *(const short8*)(apl + kt); ra_l[1] = *(const short8*)(apl + kt + 8);
                    } else {
                        // it==6: load msg tail (K=25 padded to 32)
                        const size_t mb = ((size_t)(b0 + arow) * TT + t) * VV;
                        #pragma unroll
                        for (int i = 0; i < 8; ++i) {
                            int k = xseg + i;
                            xv[i] = (k < VV) ? msg[mb + k] : 0.0f;
                        }
                    }
                } else {
                    // it==7: split + stage x-tail into buf0 (last read at it==6)
                    short8 xh, xl;
                    #pragma unroll
                    for (int i = 0; i < 8; ++i) { short h_, l_; split2(xv[i], h_, l_); xh[i] = h_; xl[i] = l_; }
                    *(short8*)&Abuf[0][0][arow][xseg] = xh;
                    *(short8*)&Abuf[0][1][arow][xseg] = xl;
                }
                __syncthreads();
            }

            // x-projection tail: chunk 16 (K=32), buf0
            {
                short8 ahf[2], alf[2];
                #pragma unroll
                for (int tm = 0; tm < 2; ++tm) {
                    int row = wm * 32 + tm * 16 + col;
                    ahf[tm] = *(const short8*)&Abuf[0][0][row][quad * 8];
                    alf[tm] = *(const short8*)&Abuf[0][1][row][quad * 8];
                }
                #pragma unroll
                for (int tm = 0; tm < 2; ++tm)
                    #pragma unroll
                    for (int g = 0; g < 4; ++g) {
                        acc[tm][g] = __builtin_amdgcn_mfma_f32_16x16x32_bf16(ahf[tm], Breg[16][g], acc[tm][g], 0, 0, 0);
                        acc[tm][g] = __builtin_amdgcn_mfma_f32_16x16x32_bf16(alf[tm], Breg[16][g], acc[tm][g], 0, 0, 0);
                    }
            }

            // cell update; h written as bf16 hi/lo planes
            // C/D layout: col=lane&15 (=n), row=quad*4+reg  [m89]
            #pragma unroll
            for (int tm = 0; tm < 2; ++tm) {
                #pragma unroll
                for (int reg = 0; reg < 4; ++reg) {
                    int b = b0 + wm * 32 + tm * 16 + quad * 4 + reg;
                    size_t idx = (size_t)b * HH + jj;
                    float i_ = fsigmoid(acc[tm][0][reg]);
                    float f_ = fsigmoid(acc[tm][1][reg]);
                    float g_ = ftanh(acc[tm][2][reg]);
                    float o_ = fsigmoid(acc[tm][3][reg]);
                    float cn = f_ * c[idx] + i_ * g_;
                    c[idx] = cn;
                    float h = o_ * ftanh(cn);
                    short hh_, hl_; split2(h, hh_, hl_);
                    hout_store:
                    houth[idx] = hh_;
                    houtl[idx] = hl_;
                }
            }
        }

        // ---- per-bp group barrier (16 blocks exchange h slices) ----
        if (t < TT - 1) {
            __syncthreads();
            __threadfence();   // release: publish h/c writes device-wide
            if (tid == 0) {
                __hip_atomic_fetch_add(&syncc[bp], 1, __ATOMIC_RELEASE, __HIP_MEMORY_SCOPE_AGENT);
                const int target = 16 * (t + 1);
                while (__hip_atomic_load(&syncc[bp], __ATOMIC_ACQUIRE, __HIP_MEMORY_SCOPE_AGENT) < target)
                    __builtin_amdgcn_s_sleep(1);
            }
            __syncthreads();
            __threadfence();   // acquire: invalidate stale cached h lines
        }
    }
}

// out[b, cls] = dot(h, W_fc[cls]) + b_fc[cls]; h = hi + lo. 4 rows/block.
__global__ __launch_bounds__(256) void fc_kernel(
    const short* __restrict__ h_hi, const short* __restrict__ h_lo,
    const float* __restrict__ W_fc, const float* __restrict__ b_fc,
    float* __restrict__ out)
{
    __shared__ float hs[4][HH];
    const int b0 = blockIdx.x * 4;
    for (int i = threadIdx.x; i < 4 * HH; i += 256) {
        int r = i >> 9, k = i & 511;
        size_t idx = (size_t)(b0 + r) * HH + k;
        unsigned uh = (unsigned)(unsigned short)h_hi[idx];
        unsigned ul = (unsigned)(unsigned short)h_lo[idx];
        hs[r][k] = __uint_as_float(uh << 16) + __uint_as_float(ul << 16);
    }
    __syncthreads();
    const int tid = threadIdx.x;
    if (tid < 2 * NC) {
        int r = tid / NC, cls = tid % NC;
        const float4* wv = (const float4*)(W_fc + (size_t)cls * HH);
        const float4* h0 = (const float4*)hs[r];
        const float4* h1 = (const float4*)hs[r + 2];
        float s0 = 0.0f, s1 = 0.0f;
        #pragma unroll 4
        for (int k = 0; k < HH / 4; ++k) {
            float4 ww = wv[k];
            float4 a0 = h0[k], a1 = h1[k];
            s0 += a0.x * ww.x + a0.y * ww.y + a0.z * ww.z + a0.w * ww.w;
            s1 += a1.x * ww.x + a1.y * ww.y + a1.z * ww.z + a1.w * ww.w;
        }
        out[(size_t)(b0 + r) * NC + cls] = s0 + b_fc[cls];
        out[(size_t)(b0 + r + 2) * NC + cls] = s1 + b_fc[cls];
    }
}

extern "C" void kernel_launch(void* const* d_in, const int* in_sizes, int n_in,
                              void* d_out, int out_size, void* d_ws, size_t ws_size,
                              hipStream_t stream) {
    const float* msg  = (const float*)d_in[0];
    const float* W_ih = (const float*)d_in[1];
    const float* W_hh = (const float*)d_in[2];
    const float* b_ih = (const float*)d_in[3];
    const float* b_hh = (const float*)d_in[4];
    const float* W_fc = (const float*)d_in[5];
    const float* b_fc = (const float*)d_in[6];
    float* out = (float*)d_out;

    // ws: syncc(256B) | c(4MB) | h0h h0l h1h h1l (2MB ea) | WTh (2.23MB)
    int*   syncc = (int*)d_ws;
    float* c   = (float*)((char*)d_ws + 256);
    short* h0h = (short*)(c + (size_t)BB * HH);
    short* h0l = h0h + (size_t)BB * HH;
    short* h1h = h0l + (size_t)BB * HH;
    short* h1l = h1h + (size_t)BB * HH;
    short* WTh = h1l + (size_t)BB * HH;

    // zero syncc + c + h0 planes (contiguous 256B + 8MB)
    hipMemsetAsync(d_ws, 0, 256 + (size_t)BB * HH * 4 + (size_t)BB * HH * 2 * 2, stream);

    prep_whh_t<<<512, 256, 0, stream>>>(W_hh, WTh);
    prep_wih_t<<<32, 256, 0, stream>>>(W_ih, WTh);

    // TT even -> final h lands in the h0 planes
    lstm_persist<<<256, 256, 0, stream>>>(msg, WTh, b_ih, b_hh,
                                          h0h, h0l, h1h, h1l, c, syncc);
    fc_kernel<<<BB / 4, 256, 0, stream>>>(h0h, h0l, W_fc, b_fc, out);
}